// Round 6
// baseline (947.673 us; speedup 1.0000x reference)
//
#include <hip/hip_runtime.h>
#include <hip/hip_cooperative_groups.h>

namespace cg = cooperative_groups;

// GIN (2x GINE conv): ONE cooperative kernel, 7 phases, 6 grid syncs.
//   P0 wprep  (weights->bf16^T, bcnt zero, ptr[N]=E)
//   P1 bin    (2048-edge LDS tile sort -> per-bucket coalesced chunks)
//   P2 csr (blocks<B) || gemm1 (grid-stride)   [independent work]
//   P3 gather1 (dual-node interleaved, scalarized csr stream) A -> B
//   P4 fused_mid: relu(B@W12+cnt*b12)@W21+b21 -> A   (through LDS)
//   P5 gather2: A -> B
//   P6 B @ W22 + cnt*b22 -> out (f32)
// R5 postmortem: smem was declared 1348 int2 = 10784B but P1 needs 21520B ->
// LDS overflow -> device fault. Fixed: 2696 int2 = 21568B.
// Fallback: if hipLaunchCooperativeKernel errors (capture incompat), launch
// the same kernel 7x with phase=0..6 (grid.sync only runs in coop mode).
// Launch-overhead model (~18us/boundary) fits R1-R4 within noise; single
// launch should recover ~110-130us vs R1's 364.

typedef unsigned int uint;
typedef unsigned short ushort;
typedef __attribute__((ext_vector_type(8))) short bf16x8;
typedef __attribute__((ext_vector_type(4))) float f32x4;

#define BSHIFT 9
#define BNODES 512
#define BIN_TILE 2048

static __device__ __forceinline__ ushort f2bf(float f) {
    uint u = __float_as_uint(f);
    uint r = (u + 0x7fffu + ((u >> 16) & 1u)) >> 16;
    return (ushort)r;
}
static __device__ __forceinline__ int rfl(int v) { return __builtin_amdgcn_readfirstlane(v); }

struct GP {
    const float* x;
    const int* src;
    const int* dst;
    const float* ea;
    const float* W11; const float* b11;
    const float* W12; const float* b12;
    const float* W21; const float* b21;
    const float* W22; const float* b22;
    const float* we1;   // W11 + 64*128 (edge-attr rows)
    const float* we2;   // W21 + 128*128
    ushort *Wt11, *Wt12, *Wt21, *Wt22;
    ushort* A_bf;       // [N][128] bf16
    uint*   B_u;        // [N][64] uint (bf16x2) ; aliases barr
    int2*   barr;       // bucket staging (aliases B_u region)
    int2*   csr;        // [E]
    int*    ptr;        // [N+1]
    int*    bcnt;       // [256]
    float*  out;        // [N][128] f32
    int N, E, B, CAP, tiles;
};

// ---------------- gather helpers ----------------

static __device__ __forceinline__ uint ldrow(const char* Ab, uint t4, uint sidx) {
    return *(const uint*)(Ab + ((sidx << 8) + t4));
}
static __device__ __forceinline__ void accum_edge(
    uint rv, uint ev, float w0x, float w0y, float w1x, float w1y,
    float& ax, float& ay) {
    float a0 = __uint_as_float(ev << 16);
    float a1 = __uint_as_float(ev & 0xffff0000u);
    float vx = __uint_as_float(rv << 16);
    float vy = __uint_as_float(rv & 0xffff0000u);
    vx = fmaf(a0, w0x, fmaf(a1, w1x, vx));
    vy = fmaf(a0, w0y, fmaf(a1, w1y, vy));
    ax += fmaxf(vx, 0.f);
    ay += fmaxf(vy, 0.f);
}
static __device__ __forceinline__ void drain_node(
    const char* Ab, uint t4, const int2* __restrict__ csr, int k, int end,
    float w0x, float w0y, float w1x, float w1y, float& ax, float& ay) {
    for (; k + 4 <= end; k += 4) {
        int2 c0 = csr[k], c1 = csr[k + 1], c2 = csr[k + 2], c3 = csr[k + 3];
        uint s0 = (uint)rfl(c0.x), e0 = (uint)rfl(c0.y);
        uint s1 = (uint)rfl(c1.x), e1 = (uint)rfl(c1.y);
        uint s2 = (uint)rfl(c2.x), e2 = (uint)rfl(c2.y);
        uint s3 = (uint)rfl(c3.x), e3 = (uint)rfl(c3.y);
        uint r0 = ldrow(Ab, t4, s0), r1 = ldrow(Ab, t4, s1);
        uint r2 = ldrow(Ab, t4, s2), r3 = ldrow(Ab, t4, s3);
        accum_edge(r0, e0, w0x, w0y, w1x, w1y, ax, ay);
        accum_edge(r1, e1, w0x, w0y, w1x, w1y, ax, ay);
        accum_edge(r2, e2, w0x, w0y, w1x, w1y, ax, ay);
        accum_edge(r3, e3, w0x, w0y, w1x, w1y, ax, ay);
    }
    for (; k < end; k++) {
        int2 c0 = csr[k];
        uint s0 = (uint)rfl(c0.x), e0 = (uint)rfl(c0.y);
        uint r0 = ldrow(Ab, t4, s0);
        accum_edge(r0, e0, w0x, w0y, w1x, w1y, ax, ay);
    }
}

// dual-node gather: each wave owns nodes (n0, n0+1); 4+4 interleaved edge
// batches double the outstanding row loads per wave.
static __device__ void gather_phase(
    const uint* __restrict__ Au, const int* __restrict__ ptr,
    const int2* __restrict__ csr, const float* __restrict__ we,
    uint* __restrict__ Bout, int N, int wid, int NW, int t) {
    const int c = 2 * t;
    const float w0x = we[c], w0y = we[c + 1];
    const float w1x = we[128 + c], w1y = we[128 + c + 1];
    const char* Ab = (const char*)Au;
    const uint t4 = (uint)t * 4u;

    for (int n0 = wid * 2; n0 < N; n0 += NW * 2) {
        const int n1 = n0 + 1;
        uint sv0 = ldrow(Ab, t4, (uint)n0);
        float ax0 = fmaxf(__uint_as_float(sv0 << 16) + w0x + w1x, 0.f);
        float ay0 = fmaxf(__uint_as_float(sv0 & 0xffff0000u) + w0y + w1y, 0.f);
        int k0 = rfl(ptr[n0]);
        int e0 = rfl(ptr[n0 + 1]);
        const bool has1 = (n1 < N);
        float ax1 = 0.f, ay1 = 0.f;
        int k1 = 0, e1 = 0;
        if (has1) {
            uint sv1 = ldrow(Ab, t4, (uint)n1);
            ax1 = fmaxf(__uint_as_float(sv1 << 16) + w0x + w1x, 0.f);
            ay1 = fmaxf(__uint_as_float(sv1 & 0xffff0000u) + w0y + w1y, 0.f);
            k1 = rfl(ptr[n1]);
            e1 = rfl(ptr[n1 + 1]);
        }
        while (k0 + 4 <= e0 && k1 + 4 <= e1) {
            int2 ca0 = csr[k0], ca1 = csr[k0 + 1], ca2 = csr[k0 + 2], ca3 = csr[k0 + 3];
            int2 cb0 = csr[k1], cb1 = csr[k1 + 1], cb2 = csr[k1 + 2], cb3 = csr[k1 + 3];
            uint sa0 = (uint)rfl(ca0.x), ea0 = (uint)rfl(ca0.y);
            uint sa1 = (uint)rfl(ca1.x), ea1 = (uint)rfl(ca1.y);
            uint sa2 = (uint)rfl(ca2.x), ea2 = (uint)rfl(ca2.y);
            uint sa3 = (uint)rfl(ca3.x), ea3 = (uint)rfl(ca3.y);
            uint sb0 = (uint)rfl(cb0.x), eb0 = (uint)rfl(cb0.y);
            uint sb1 = (uint)rfl(cb1.x), eb1 = (uint)rfl(cb1.y);
            uint sb2 = (uint)rfl(cb2.x), eb2 = (uint)rfl(cb2.y);
            uint sb3 = (uint)rfl(cb3.x), eb3 = (uint)rfl(cb3.y);
            uint ra0 = ldrow(Ab, t4, sa0), ra1 = ldrow(Ab, t4, sa1);
            uint ra2 = ldrow(Ab, t4, sa2), ra3 = ldrow(Ab, t4, sa3);
            uint rb0 = ldrow(Ab, t4, sb0), rb1 = ldrow(Ab, t4, sb1);
            uint rb2 = ldrow(Ab, t4, sb2), rb3 = ldrow(Ab, t4, sb3);
            accum_edge(ra0, ea0, w0x, w0y, w1x, w1y, ax0, ay0);
            accum_edge(ra1, ea1, w0x, w0y, w1x, w1y, ax0, ay0);
            accum_edge(ra2, ea2, w0x, w0y, w1x, w1y, ax0, ay0);
            accum_edge(ra3, ea3, w0x, w0y, w1x, w1y, ax0, ay0);
            accum_edge(rb0, eb0, w0x, w0y, w1x, w1y, ax1, ay1);
            accum_edge(rb1, eb1, w0x, w0y, w1x, w1y, ax1, ay1);
            accum_edge(rb2, eb2, w0x, w0y, w1x, w1y, ax1, ay1);
            accum_edge(rb3, eb3, w0x, w0y, w1x, w1y, ax1, ay1);
            k0 += 4; k1 += 4;
        }
        drain_node(Ab, t4, csr, k0, e0, w0x, w0y, w1x, w1y, ax0, ay0);
        uint o0 = (uint)f2bf(ax0) | ((uint)f2bf(ay0) << 16);
        __builtin_nontemporal_store(o0, Bout + (long)n0 * 64 + t);
        if (has1) {
            drain_node(Ab, t4, csr, k1, e1, w0x, w0y, w1x, w1y, ax1, ay1);
            uint o1 = (uint)f2bf(ax1) | ((uint)f2bf(ay1) << 16);
            __builtin_nontemporal_store(o1, Bout + (long)n1 * 64 + t);
        }
    }
}

// ---------------- MFMA GEMM body: C[rowBase..+64][128] = A @ W[K][128] + bias ----------------

template <int K, bool IN_F32, bool OUT_BF16, bool USE_CNT>
static __device__ __forceinline__ void gemm_body(
    const void* __restrict__ Ain, const ushort* __restrict__ Wt,
    const float* __restrict__ bias, const int* __restrict__ ptr,
    void* __restrict__ Cout, int N, int tid, long rowBase) {
    constexpr int KS = K / 32;
    const int wave = tid >> 6;
    const int lane = tid & 63;
    const int m = lane & 15, quad = lane >> 4;

    bf16x8 bfrag[2][KS];
#pragma unroll
    for (int ct = 0; ct < 2; ct++) {
        int col = (wave * 2 + ct) * 16 + m;
#pragma unroll
        for (int ks = 0; ks < KS; ks++)
            bfrag[ct][ks] = *(const bf16x8*)(Wt + (long)col * K + ks * 32 + quad * 8);
    }

#pragma unroll
    for (int rt = 0; rt < 4; rt++) {
        long row = rowBase + rt * 16 + m;
        long rc = row < N ? row : (long)N - 1;
        bf16x8 afrag[KS];
        if (IN_F32) {
            const float* arow = (const float*)Ain + rc * K;
#pragma unroll
            for (int ks = 0; ks < KS; ks++) {
                float4 lo = *(const float4*)(arow + ks * 32 + quad * 8);
                float4 hi = *(const float4*)(arow + ks * 32 + quad * 8 + 4);
                bf16x8 f;
                f[0] = (short)f2bf(lo.x); f[1] = (short)f2bf(lo.y);
                f[2] = (short)f2bf(lo.z); f[3] = (short)f2bf(lo.w);
                f[4] = (short)f2bf(hi.x); f[5] = (short)f2bf(hi.y);
                f[6] = (short)f2bf(hi.z); f[7] = (short)f2bf(hi.w);
                afrag[ks] = f;
            }
        } else {
            const ushort* arow = (const ushort*)Ain + rc * K;
#pragma unroll
            for (int ks = 0; ks < KS; ks++)
                afrag[ks] = *(const bf16x8*)(arow + ks * 32 + quad * 8);
        }

#pragma unroll
        for (int ct = 0; ct < 2; ct++) {
            f32x4 acc = {0.f, 0.f, 0.f, 0.f};
#pragma unroll
            for (int ks = 0; ks < KS; ks++)
                acc = __builtin_amdgcn_mfma_f32_16x16x32_bf16(afrag[ks], bfrag[ct][ks], acc, 0, 0, 0);

            int col = (wave * 2 + ct) * 16 + m;
            float b = bias[col];
#pragma unroll
            for (int r = 0; r < 4; r++) {
                long orow = rowBase + rt * 16 + quad * 4 + r;
                if (orow < N) {
                    float v = acc[r];
                    if (USE_CNT) v += b * (float)(ptr[orow + 1] - ptr[orow] + 1);
                    else v += b;
                    if (OUT_BF16) ((ushort*)Cout)[orow * 128 + col] = f2bf(v);
                    else ((float*)Cout)[orow * 128 + col] = v;
                }
            }
        }
    }
}

// ---------------- the single cooperative kernel (phase<0: all, with grid.sync) ----------------

__global__ __launch_bounds__(256) void gin_coop(GP P, int phase) {
    __shared__ int2 smem[2696];   // 21568 B: bin 21520 / mid ts 17408 / csr 4116
    cg::grid_group grid = cg::this_grid();
    const bool all = (phase < 0);
    const int tid = threadIdx.x;
    const int bid = (int)blockIdx.x;
    const int G = (int)gridDim.x;
    const int lane = tid & 63;
    const int wv = tid >> 6;

    // ---- P0: weight transpose + init ----
    if (all || phase == 0) {
        for (int idx = bid * 256 + tid; idx < 448 * 128; idx += G * 256) {
            const float* W; ushort* Wt; int K; int off;
            if (idx < 64 * 128)        { W = P.W11; Wt = P.Wt11; K = 64;  off = idx; }
            else if (idx < 192 * 128)  { W = P.W12; Wt = P.Wt12; K = 128; off = idx - 64 * 128; }
            else if (idx < 320 * 128)  { W = P.W21; Wt = P.Wt21; K = 128; off = idx - 192 * 128; }
            else                       { W = P.W22; Wt = P.Wt22; K = 128; off = idx - 320 * 128; }
            int k = off >> 7, n = off & 127;
            Wt[n * K + k] = f2bf(W[k * 128 + n]);
        }
        if (bid == 0) { P.bcnt[tid] = 0; if (tid == 0) P.ptr[P.N] = P.E; }
    }
    if (all) grid.sync();

    // ---- P1: bin (2048-edge LDS tile sort -> coalesced bucket appends) ----
    if (all || phase == 1) {
        int2* sorted = smem;                                   // 2048 int2 = 16384 B
        unsigned char* bof = (unsigned char*)(smem + 2048);    // 2048 B
        int* hist  = (int*)(bof + 2048);                       // 256 ints
        int* bbase = hist + 256;
        int* gbase = bbase + 256;
        int* wtot  = gbase + 256;                              // 4 ints -> 21520 B total
        const int T = (P.E + BIN_TILE - 1) / BIN_TILE;
        for (int tile = bid; tile < T; tile += G) {
            const int tb = tile * BIN_TILE;
            int n = P.E - tb; if (n > BIN_TILE) n = BIN_TILE;
            hist[tid] = 0;
            __syncthreads();
            int2 ent[8]; int bk[8]; int rk[8];
#pragma unroll
            for (int kk = 0; kk < 8; kk++) {
                int i = kk * 256 + tid;
                bk[kk] = -1;
                if (i < n) {
                    int e = tb + i;
                    int s = P.src[e], d = P.dst[e];
                    float2 a = reinterpret_cast<const float2*>(P.ea)[e];
                    int b = d >> BSHIFT;
                    ent[kk].x = s | ((d & (BNODES - 1)) << 17);
                    ent[kk].y = (int)((uint)f2bf(a.x) | ((uint)f2bf(a.y) << 16));
                    bk[kk] = b;
                    rk[kk] = atomicAdd(&hist[b], 1);
                }
            }
            __syncthreads();
            int hv = hist[tid], inc = hv;
#pragma unroll
            for (int off = 1; off < 64; off <<= 1) {
                int tt = __shfl_up(inc, off, 64);
                if (lane >= off) inc += tt;
            }
            if (lane == 63) wtot[wv] = inc;
            __syncthreads();
            if (tid == 0) { int run = 0; for (int j = 0; j < 4; j++) { int tt = wtot[j]; wtot[j] = run; run += tt; } }
            __syncthreads();
            bbase[tid] = inc - hv + wtot[wv];
            if (tid < P.B && hv > 0) gbase[tid] = atomicAdd(&P.bcnt[tid], hv);
            __syncthreads();
#pragma unroll
            for (int kk = 0; kk < 8; kk++)
                if (bk[kk] >= 0) {
                    int pp = bbase[bk[kk]] + rk[kk];
                    sorted[pp] = ent[kk];
                    bof[pp] = (unsigned char)bk[kk];
                }
            __syncthreads();
            for (int i = tid; i < n; i += 256) {
                int b = bof[i];
                P.barr[(long)b * P.CAP + gbase[b] + (i - bbase[b])] = sorted[i];
            }
            __syncthreads();
        }
    }
    if (all) grid.sync();

    // ---- P2: per-bucket CSR (blocks < B) || layer-1 GEMM (rest) ----
    if (all || phase == 2) {
        if (bid < P.B) {
            int* chist = (int*)smem;       // 512 ints
            int* clptr = chist + 512;      // 512 ints
            int* cwtot = clptr + 512;      // 4
            int* csb   = cwtot + 4;        // 1   -> 4116 B total
            const int g = bid;
            const int cnt = P.bcnt[g];
            if (tid == 0) csb[0] = 0;
            chist[tid] = 0; chist[tid + 256] = 0;
            __syncthreads();
            if (tid < g) atomicAdd(csb, P.bcnt[tid]);   // bucket base (parallel)
            const int2* my = P.barr + (long)g * P.CAP;
            for (int i = tid; i < cnt; i += 256)
                atomicAdd(&chist[((uint)my[i].x) >> 17], 1);
            __syncthreads();
            int v0 = chist[2 * tid], v1 = chist[2 * tid + 1];
            int s = v0 + v1, inc = s;
#pragma unroll
            for (int off = 1; off < 64; off <<= 1) {
                int tt = __shfl_up(inc, off, 64);
                if (lane >= off) inc += tt;
            }
            if (lane == 63) cwtot[wv] = inc;
            __syncthreads();
            if (tid == 0) { int run = 0; for (int j = 0; j < 4; j++) { int tt = cwtot[j]; cwtot[j] = run; run += tt; } }
            __syncthreads();
            const int base = csb[0];
            int excl = inc - s + cwtot[wv];
            clptr[2 * tid] = excl;
            clptr[2 * tid + 1] = excl + v0;
            int gn = g * BNODES + 2 * tid;
            if (gn < P.N) P.ptr[gn] = base + excl;
            if (gn + 1 < P.N) P.ptr[gn + 1] = base + excl + v0;
            __syncthreads();
            for (int i = tid; i < cnt; i += 256) {
                int2 e = my[i];
                int pos = base + atomicAdd(&clptr[((uint)e.x) >> 17], 1);
                int2 o; o.x = e.x & 0x1FFFF; o.y = e.y;
                P.csr[pos] = o;
            }
        } else {
            for (int t2 = bid - P.B; t2 < P.tiles; t2 += G - P.B)
                gemm_body<64, true, true, false>(P.x, P.Wt11, P.b11, nullptr,
                                                 P.A_bf, P.N, tid, (long)t2 * 64);
        }
    }
    if (all) grid.sync();

    // ---- P3: gather1  A -> B ----
    if (all || phase == 3)
        gather_phase((const uint*)P.A_bf, P.ptr, P.csr, P.we1, P.B_u, P.N,
                     bid * 4 + wv, G * 4, lane);
    if (all) grid.sync();

    // ---- P4: fused middle GEMMs: relu(B@W12+cnt*b12)@W21+b21 -> A ----
    if (all || phase == 4) {
        ushort* ts = (ushort*)smem;    // [64][136] = 17408 B
        const int m = lane & 15, quad = lane >> 4;
        for (int t2 = bid; t2 < P.tiles; t2 += G) {
            const long rowBase = (long)t2 * 64;
            bf16x8 bfrag[2][4];
#pragma unroll
            for (int ct = 0; ct < 2; ct++) {
                int col = (wv * 2 + ct) * 16 + m;
#pragma unroll
                for (int ks = 0; ks < 4; ks++)
                    bfrag[ct][ks] = *(const bf16x8*)(P.Wt12 + (long)col * 128 + ks * 32 + quad * 8);
            }
#pragma unroll
            for (int rt = 0; rt < 4; rt++) {
                long row = rowBase + rt * 16 + m;
                long rc = row < P.N ? row : (long)P.N - 1;
                const ushort* arow = (const ushort*)P.B_u + rc * 128;
                bf16x8 af[4];
#pragma unroll
                for (int ks = 0; ks < 4; ks++)
                    af[ks] = *(const bf16x8*)(arow + ks * 32 + quad * 8);
                float cntf[4];
#pragma unroll
                for (int r = 0; r < 4; r++) {
                    long grow = rowBase + rt * 16 + quad * 4 + r;
                    cntf[r] = (grow < P.N) ? (float)(P.ptr[grow + 1] - P.ptr[grow] + 1) : 1.f;
                }
#pragma unroll
                for (int ct = 0; ct < 2; ct++) {
                    f32x4 a = {0.f, 0.f, 0.f, 0.f};
#pragma unroll
                    for (int ks = 0; ks < 4; ks++)
                        a = __builtin_amdgcn_mfma_f32_16x16x32_bf16(af[ks], bfrag[ct][ks], a, 0, 0, 0);
                    int col = (wv * 2 + ct) * 16 + m;
                    float b = P.b12[col];
#pragma unroll
                    for (int r = 0; r < 4; r++) {
                        int rowi = rt * 16 + quad * 4 + r;
                        ts[rowi * 136 + col] = f2bf(fmaxf(a[r] + b * cntf[r], 0.f));
                    }
                }
            }
            __syncthreads();
#pragma unroll
            for (int ct = 0; ct < 2; ct++) {
                int col = (wv * 2 + ct) * 16 + m;
#pragma unroll
                for (int ks = 0; ks < 4; ks++)
                    bfrag[ct][ks] = *(const bf16x8*)(P.Wt21 + (long)col * 128 + ks * 32 + quad * 8);
            }
#pragma unroll
            for (int rt = 0; rt < 4; rt++) {
                const ushort* lr = ts + (rt * 16 + m) * 136;
                bf16x8 af[4];
#pragma unroll
                for (int ks = 0; ks < 4; ks++)
                    af[ks] = *(const bf16x8*)(lr + ks * 32 + quad * 8);
#pragma unroll
                for (int ct = 0; ct < 2; ct++) {
                    f32x4 a = {0.f, 0.f, 0.f, 0.f};
#pragma unroll
                    for (int ks = 0; ks < 4; ks++)
                        a = __builtin_amdgcn_mfma_f32_16x16x32_bf16(af[ks], bfrag[ct][ks], a, 0, 0, 0);
                    int col = (wv * 2 + ct) * 16 + m;
                    float b = P.b21[col];
#pragma unroll
                    for (int r = 0; r < 4; r++) {
                        long grow = rowBase + rt * 16 + quad * 4 + r;
                        if (grow < P.N) P.A_bf[grow * 128 + col] = f2bf(a[r] + b);
                    }
                }
            }
            __syncthreads();
        }
    }
    if (all) grid.sync();

    // ---- P5: gather2  A -> B ----
    if (all || phase == 5)
        gather_phase((const uint*)P.A_bf, P.ptr, P.csr, P.we2, P.B_u, P.N,
                     bid * 4 + wv, G * 4, lane);
    if (all) grid.sync();

    // ---- P6: final GEMM: B @ W22 + cnt*b22 -> out (f32) ----
    if (all || phase == 6)
        for (int t2 = bid; t2 < P.tiles; t2 += G)
            gemm_body<128, false, false, true>((const ushort*)P.B_u, P.Wt22, P.b22,
                                               P.ptr, P.out, P.N, tid, (long)t2 * 64);
}

// ---------------- launch ----------------

extern "C" void kernel_launch(void* const* d_in, const int* in_sizes, int n_in,
                              void* d_out, int out_size, void* d_ws, size_t ws_size,
                              hipStream_t stream) {
    const float* x   = (const float*)d_in[0];
    const int*   ei  = (const int*)d_in[1];
    const float* ea  = (const float*)d_in[2];

    const int N = in_sizes[0] / 64;
    const int E = in_sizes[1] / 2;
    const int B = (N + BNODES - 1) >> BSHIFT;   // 196 buckets
    const int CAP = E / B + 2048;               // mean + ~22 sigma slack

    char* p = (char*)d_ws;
    ushort* A_bf = (ushort*)p;        p += (size_t)N * 128 * 2;   // 25.6 MB
    uint*   B_u  = (uint*)p;
    int2*   barr = (int2*)p;          p += (size_t)N * 64 * 4;    // 25.6 MB (barr 16.0 MB alias; consumed in P2 before B written in P3)
    int2*   csr  = (int2*)p;          p += (size_t)E * 8;         // 12.8 MB
    int*    ptr  = (int*)p;           p += (size_t)(N + 1) * 4;
    int*    bcnt = (int*)p;           p += 256 * 4;
    ushort* Wt11 = (ushort*)p;        p += (size_t)64 * 128 * 2;
    ushort* Wt12 = (ushort*)p;        p += (size_t)128 * 128 * 2;
    ushort* Wt21 = (ushort*)p;        p += (size_t)128 * 128 * 2;
    ushort* Wt22 = (ushort*)p;

    GP P;
    P.x = x; P.src = ei; P.dst = ei + E; P.ea = ea;
    P.W11 = (const float*)d_in[3];  P.b11 = (const float*)d_in[4];
    P.W12 = (const float*)d_in[5];  P.b12 = (const float*)d_in[6];
    P.W21 = (const float*)d_in[7];  P.b21 = (const float*)d_in[8];
    P.W22 = (const float*)d_in[9];  P.b22 = (const float*)d_in[10];
    P.we1 = P.W11 + 64 * 128;
    P.we2 = P.W21 + 128 * 128;
    P.Wt11 = Wt11; P.Wt12 = Wt12; P.Wt21 = Wt21; P.Wt22 = Wt22;
    P.A_bf = A_bf; P.B_u = B_u; P.barr = barr; P.csr = csr;
    P.ptr = ptr; P.bcnt = bcnt; P.out = (float*)d_out;
    P.N = N; P.E = E; P.B = B; P.CAP = CAP;
    P.tiles = (N + 63) / 64;

    // co-resident grid size (cached): occupancy * CU count, capped.
    static int Gcache = 0;
    if (Gcache == 0) {
        int maxB = 0;
        if (hipOccupancyMaxActiveBlocksPerMultiprocessor(
                &maxB, reinterpret_cast<const void*>(&gin_coop), 256, 0) != hipSuccess || maxB < 1)
            maxB = 4;
        int cus = 0;
        if (hipDeviceGetAttribute(&cus, hipDeviceAttributeMultiprocessorCount, 0) != hipSuccess || cus < 1)
            cus = 256;
        long g = (long)maxB * cus;
        if (g > 2048) g = 2048;
        if (g < 256) g = 256;   // csr phase needs >= B(196) blocks
        Gcache = (int)g;
    }

    int phase = -1;
    void* args[] = { (void*)&P, (void*)&phase };
    hipError_t err = hipLaunchCooperativeKernel(
        reinterpret_cast<const void*>(&gin_coop),
        dim3(Gcache), dim3(256), args, 0, stream);
    if (err != hipSuccess) {
        // fallback: 7 ordinary launches, phase-by-phase (grid.sync skipped)
        for (int ph = 0; ph < 7; ph++)
            gin_coop<<<Gcache, 256, 0, stream>>>(P, ph);
    }
}

// Round 7
// 464.605 us; speedup vs baseline: 2.0397x; 2.0397x over previous
//
#include <hip/hip_runtime.h>

// GIN (2x GINE conv): bucketed CSR build + CSR gather fused into the
// following MFMA GEMMs through LDS. 4 launches + 1 memset:
//   M0 memset bcnt=0
//   K1 wprep||bin   (blocks<WB transpose weights; rest: 4096-edge LDS sort)
//   K2 csr||gemm1   (196 csr blocks + 782 gemm tiles; independent)
//   K3 gather_mid: dual-node gather(A)->LDS; relu(ts@W12+cnt*b12)@W21+b21->A2
//   K4 gather_out: dual-node gather(A2)->LDS; ts@W22+cnt*b22 -> out (f32, nt)
// R6 postmortem: coop single-kernel = ~1050us; grid.sync costs ~100us+ each
// (one arrival cacheline RMW'd by 1024 blocks bouncing across 8 XCD L2s).
// Multi-kernel + graph-captured launches is the cheaper sync.
// R2/R3 anomaly: fused gather is occupancy-invariant ~110us (2x standalone)
// with same bytes/VALU -> codegen lost memory-level parallelism. Fix: R6's
// proven dual-node interleave (two independent 4-deep load chains per wave).

typedef unsigned int uint;
typedef unsigned short ushort;
typedef __attribute__((ext_vector_type(8))) short bf16x8;
typedef __attribute__((ext_vector_type(4))) float f32x4;

#define BSHIFT 9             // 512 nodes per bucket -> 196 buckets
#define BNODES (1 << BSHIFT)

static __device__ __forceinline__ ushort f2bf(float f) {
    uint u = __float_as_uint(f);
    uint r = (u + 0x7fffu + ((u >> 16) & 1u)) >> 16;
    return (ushort)r;
}
static __device__ __forceinline__ int rfl(int v) { return __builtin_amdgcn_readfirstlane(v); }

// ---------------- K1: weight prep (blocks < WB) || edge binning (rest) ----------------
// bin: entry.x = src | (dloc<<17) (src<2^17, dloc<2^9), entry.y = ea bf16x2

__global__ __launch_bounds__(512) void wprep_bin(
    const float* __restrict__ W11, const float* __restrict__ W12,
    const float* __restrict__ W21, const float* __restrict__ W22,
    ushort* Wt11, ushort* Wt12, ushort* Wt21, ushort* Wt22,
    const int* __restrict__ src, const int* __restrict__ dst,
    const float* __restrict__ ea, int* __restrict__ bcnt,
    int2* __restrict__ barr, int CAP, int N, int E, int B, int WB,
    int* __restrict__ ptr) {
    __shared__ int hist[256];
    __shared__ int bbase[256];
    __shared__ int gbase[256];
    __shared__ int wtot[4];
    __shared__ int2 sorted[4096];
    __shared__ unsigned char bof[4096];
    const int tid = threadIdx.x;
    const int lane = tid & 63;

    if ((int)blockIdx.x < WB) {
        // ---- weight transpose: W[K][128] f32 -> Wt[128][K] bf16 ----
        int idx = blockIdx.x * 512 + tid;
        if (idx == 0) ptr[N] = E;
        if (idx < 448 * 128) {
            const float* W; ushort* Wt; int K; int off;
            if (idx < 64 * 128)        { W = W11; Wt = Wt11; K = 64;  off = idx; }
            else if (idx < 192 * 128)  { W = W12; Wt = Wt12; K = 128; off = idx - 64 * 128; }
            else if (idx < 320 * 128)  { W = W21; Wt = Wt21; K = 128; off = idx - 192 * 128; }
            else                       { W = W22; Wt = Wt22; K = 128; off = idx - 320 * 128; }
            int k = off >> 7, n = off & 127;
            Wt[n * K + k] = f2bf(W[k * 128 + n]);
        }
        return;
    }

    // ---- binning: 4096-edge tile sort in LDS, coalesced chunk appends ----
    const int tileBase = ((int)blockIdx.x - WB) * 4096;
    int n = E - tileBase; if (n > 4096) n = 4096; if (n <= 0) return;
    if (tid < 256) hist[tid] = 0;
    __syncthreads();

    int2 ent[8]; int bk[8]; int rk[8];
#pragma unroll
    for (int kk = 0; kk < 8; kk++) {
        int i = kk * 512 + tid;
        bk[kk] = -1;
        if (i < n) {
            int e = tileBase + i;
            int s = src[e], d = dst[e];
            float2 a = reinterpret_cast<const float2*>(ea)[e];
            int b = d >> BSHIFT;
            int dloc = d & (BNODES - 1);
            ent[kk].x = s | (dloc << 17);
            ent[kk].y = (int)((uint)f2bf(a.x) | ((uint)f2bf(a.y) << 16));
            bk[kk] = b;
            rk[kk] = atomicAdd(&hist[b], 1);
        }
    }
    __syncthreads();
    int hv = (tid < 256) ? hist[tid] : 0;
    int inc = hv;
#pragma unroll
    for (int off = 1; off < 64; off <<= 1) {
        int tt = __shfl_up(inc, off, 64);
        if (lane >= off) inc += tt;
    }
    if ((tid >> 6) < 4 && lane == 63) wtot[tid >> 6] = inc;
    __syncthreads();
    if (tid == 0) { int run = 0; for (int i = 0; i < 4; i++) { int tt = wtot[i]; wtot[i] = run; run += tt; } }
    __syncthreads();
    if (tid < 256) bbase[tid] = inc - hv + wtot[tid >> 6];
    if (tid < B && hv > 0) gbase[tid] = atomicAdd(&bcnt[tid], hv);
    __syncthreads();
#pragma unroll
    for (int kk = 0; kk < 8; kk++) {
        if (bk[kk] >= 0) {
            int p = bbase[bk[kk]] + rk[kk];
            sorted[p] = ent[kk];
            bof[p] = (unsigned char)bk[kk];
        }
    }
    __syncthreads();
    for (int i = tid; i < n; i += 512) {
        int b = bof[i];
        barr[(long)b * CAP + gbase[b] + (i - bbase[b])] = sorted[i];
    }
}

// ---------------- per-bucket exact CSR (512-node bucket, 512 threads) ----------------

static __device__ void csr_body(const int2* __restrict__ barr, const int* __restrict__ bcnt,
                                int CAP, int N, int2* __restrict__ csr, int* __restrict__ ptr) {
    __shared__ int hist[BNODES];
    __shared__ int lptr[BNODES];
    __shared__ int wtot[8];
    __shared__ int sbase;
    const int g = blockIdx.x;
    const int tid = threadIdx.x;
    const int lane = tid & 63;
    const int cnt = bcnt[g];
    if (tid == 0) sbase = 0;
    hist[tid] = 0;
    __syncthreads();
    if (tid < g) atomicAdd(&sbase, bcnt[tid]);   // bucket base (parallel)
    const int2* my = barr + (long)g * CAP;
    for (int i = tid; i < cnt; i += 512)
        atomicAdd(&hist[((uint)my[i].x) >> 17], 1);
    __syncthreads();
    int v = hist[tid];
    int inc = v;
#pragma unroll
    for (int off = 1; off < 64; off <<= 1) {
        int tt = __shfl_up(inc, off, 64);
        if (lane >= off) inc += tt;
    }
    if (lane == 63) wtot[tid >> 6] = inc;
    __syncthreads();
    if (tid == 0) { int run = 0; for (int i = 0; i < 8; i++) { int tt = wtot[i]; wtot[i] = run; run += tt; } }
    __syncthreads();
    const int base = sbase;
    int excl = inc - v + wtot[tid >> 6];
    lptr[tid] = excl;
    int gnode = g * BNODES + tid;
    if (gnode < N) ptr[gnode] = base + excl;
    __syncthreads();
    for (int i = tid; i < cnt; i += 512) {
        int2 e = my[i];
        int pos = base + atomicAdd(&lptr[((uint)e.x) >> 17], 1);
        int2 o; o.x = e.x & 0x1FFFF; o.y = e.y;
        csr[pos] = o;
    }
}

// ---------------- MFMA GEMM body: C[rowBase..+64][128] = A @ W[K][128] + bias ----------------

template <int K, bool IN_F32, bool OUT_BF16, bool USE_CNT>
static __device__ __forceinline__ void gemm_body(
    const void* __restrict__ Ain, const ushort* __restrict__ Wt,
    const float* __restrict__ bias, const int* __restrict__ ptr,
    void* __restrict__ Cout, int N, int tid, long rowBase) {
    constexpr int KS = K / 32;
    const int wave = tid >> 6;
    const int lane = tid & 63;
    const int m = lane & 15, quad = lane >> 4;

    bf16x8 bfrag[2][KS];
#pragma unroll
    for (int ct = 0; ct < 2; ct++) {
        int col = (wave * 2 + ct) * 16 + m;
#pragma unroll
        for (int ks = 0; ks < KS; ks++)
            bfrag[ct][ks] = *(const bf16x8*)(Wt + (long)col * K + ks * 32 + quad * 8);
    }

#pragma unroll
    for (int rt = 0; rt < 4; rt++) {
        long row = rowBase + rt * 16 + m;
        long rc = row < N ? row : (long)N - 1;
        bf16x8 afrag[KS];
        if (IN_F32) {
            const float* arow = (const float*)Ain + rc * K;
#pragma unroll
            for (int ks = 0; ks < KS; ks++) {
                float4 lo = *(const float4*)(arow + ks * 32 + quad * 8);
                float4 hi = *(const float4*)(arow + ks * 32 + quad * 8 + 4);
                bf16x8 f;
                f[0] = (short)f2bf(lo.x); f[1] = (short)f2bf(lo.y);
                f[2] = (short)f2bf(lo.z); f[3] = (short)f2bf(lo.w);
                f[4] = (short)f2bf(hi.x); f[5] = (short)f2bf(hi.y);
                f[6] = (short)f2bf(hi.z); f[7] = (short)f2bf(hi.w);
                afrag[ks] = f;
            }
        } else {
            const ushort* arow = (const ushort*)Ain + rc * K;
#pragma unroll
            for (int ks = 0; ks < KS; ks++)
                afrag[ks] = *(const bf16x8*)(arow + ks * 32 + quad * 8);
        }

#pragma unroll
        for (int ct = 0; ct < 2; ct++) {
            f32x4 acc = {0.f, 0.f, 0.f, 0.f};
#pragma unroll
            for (int ks = 0; ks < KS; ks++)
                acc = __builtin_amdgcn_mfma_f32_16x16x32_bf16(afrag[ks], bfrag[ct][ks], acc, 0, 0, 0);

            int col = (wave * 2 + ct) * 16 + m;
            float b = bias[col];
#pragma unroll
            for (int r = 0; r < 4; r++) {
                long orow = rowBase + rt * 16 + quad * 4 + r;
                if (orow < N) {
                    float v = acc[r];
                    if (USE_CNT) v += b * (float)(ptr[orow + 1] - ptr[orow] + 1);
                    else v += b;
                    if (OUT_BF16) ((ushort*)Cout)[orow * 128 + col] = f2bf(v);
                    else ((float*)Cout)[orow * 128 + col] = v;
                }
            }
        }
    }
}

// ---------------- K2: bucket CSR (blocks < B) || layer-1 GEMM ----------------

__global__ __launch_bounds__(512) void csr_gemm1(
    const int2* __restrict__ barr, const int* __restrict__ bcnt, int CAP, int N,
    int2* __restrict__ csr, int* __restrict__ ptr, int CSRB,
    const float* __restrict__ x, const ushort* __restrict__ Wt11,
    const float* __restrict__ b11, ushort* __restrict__ A_bf) {
    if ((int)blockIdx.x < CSRB) {
        csr_body(barr, bcnt, CAP, N, csr, ptr);
    } else {
        int bid = blockIdx.x - CSRB;
        int sub = threadIdx.x >> 8;  // two 64-row tiles per 512-thread block
        gemm_body<64, true, true, false>(x, Wt11, b11, nullptr, A_bf, N,
                                         threadIdx.x & 255,
                                         (long)bid * 128 + sub * 64);
    }
}

// ---------------- gather helpers (R6-proven dual-node interleave) ----------------

static __device__ __forceinline__ uint ldrow(const char* Ab, uint t4, uint sidx) {
    return *(const uint*)(Ab + ((sidx << 8) + t4));
}
static __device__ __forceinline__ void accum_edge(
    uint rv, uint ev, float w0x, float w0y, float w1x, float w1y,
    float& ax, float& ay) {
    float a0 = __uint_as_float(ev << 16);
    float a1 = __uint_as_float(ev & 0xffff0000u);
    float vx = __uint_as_float(rv << 16);
    float vy = __uint_as_float(rv & 0xffff0000u);
    vx = fmaf(a0, w0x, fmaf(a1, w1x, vx));
    vy = fmaf(a0, w0y, fmaf(a1, w1y, vy));
    ax += fmaxf(vx, 0.f);
    ay += fmaxf(vy, 0.f);
}
static __device__ __forceinline__ void drain_node(
    const char* Ab, uint t4, const int2* __restrict__ csr, int k, int end,
    float w0x, float w0y, float w1x, float w1y, float& ax, float& ay) {
    for (; k + 4 <= end; k += 4) {
        int2 c0 = csr[k], c1 = csr[k + 1], c2 = csr[k + 2], c3 = csr[k + 3];
        uint s0 = (uint)rfl(c0.x), e0 = (uint)rfl(c0.y);
        uint s1 = (uint)rfl(c1.x), e1 = (uint)rfl(c1.y);
        uint s2 = (uint)rfl(c2.x), e2 = (uint)rfl(c2.y);
        uint s3 = (uint)rfl(c3.x), e3 = (uint)rfl(c3.y);
        uint r0 = ldrow(Ab, t4, s0), r1 = ldrow(Ab, t4, s1);
        uint r2 = ldrow(Ab, t4, s2), r3 = ldrow(Ab, t4, s3);
        accum_edge(r0, e0, w0x, w0y, w1x, w1y, ax, ay);
        accum_edge(r1, e1, w0x, w0y, w1x, w1y, ax, ay);
        accum_edge(r2, e2, w0x, w0y, w1x, w1y, ax, ay);
        accum_edge(r3, e3, w0x, w0y, w1x, w1y, ax, ay);
    }
    for (; k < end; k++) {
        int2 c0 = csr[k];
        uint s0 = (uint)rfl(c0.x), e0 = (uint)rfl(c0.y);
        uint r0 = ldrow(Ab, t4, s0);
        accum_edge(r0, e0, w0x, w0y, w1x, w1y, ax, ay);
    }
}

// dual-node gather into LDS tile: wave owns 16 rows, processed as 8 pairs
// with interleaved 4+4 edge batches -> two independent load chains per wave.
// ts layout: [64 rows][68 uints] (=136 shorts/row), conflict-free for MFMA
// A-fragment reads.
static __device__ __forceinline__ void gather_lds(
    const uint* __restrict__ Au, const int* __restrict__ ptr,
    const int2* __restrict__ csr, const float* __restrict__ we,
    uint* __restrict__ ts_u, int N, int tid, int rowBase) {
    const int w = tid >> 6;
    const int t = tid & 63;
    const int c = 2 * t;
    const float w0x = we[c], w0y = we[c + 1];
    const float w1x = we[128 + c], w1y = we[128 + c + 1];
    const char* Ab = (const char*)Au;
    const uint t4 = (uint)t * 4u;
    const int nodeBase = rowBase + w * 16;
    if (nodeBase >= N) return;
    int kNext = rfl(ptr[nodeBase]);      // carried: ptr[n+1] of pair i is ptr[n] of pair i+1

    for (int i = 0; i < 16; i += 2) {
        const int n0 = nodeBase + i;
        if (n0 >= N) break;              // wave-uniform
        const int n1 = n0 + 1;
        const bool h1 = (n1 < N);
        int k0 = kNext;
        int e0 = rfl(ptr[n0 + 1]);
        int k1 = e0, e1 = e0;            // h1==false -> empty range for node1
        if (h1) { e1 = rfl(ptr[n1 + 1]); kNext = e1; }

        uint sv0 = ldrow(Ab, t4, (uint)n0);
        float ax0 = fmaxf(__uint_as_float(sv0 << 16) + w0x + w1x, 0.f);
        float ay0 = fmaxf(__uint_as_float(sv0 & 0xffff0000u) + w0y + w1y, 0.f);
        float ax1 = 0.f, ay1 = 0.f;
        if (h1) {
            uint sv1 = ldrow(Ab, t4, (uint)n1);
            ax1 = fmaxf(__uint_as_float(sv1 << 16) + w0x + w1x, 0.f);
            ay1 = fmaxf(__uint_as_float(sv1 & 0xffff0000u) + w0y + w1y, 0.f);
        }
        while (k0 + 4 <= e0 && k1 + 4 <= e1) {
            int2 ca0 = csr[k0], ca1 = csr[k0 + 1], ca2 = csr[k0 + 2], ca3 = csr[k0 + 3];
            int2 cb0 = csr[k1], cb1 = csr[k1 + 1], cb2 = csr[k1 + 2], cb3 = csr[k1 + 3];
            uint sa0 = (uint)rfl(ca0.x), ea0 = (uint)rfl(ca0.y);
            uint sa1 = (uint)rfl(ca1.x), ea1 = (uint)rfl(ca1.y);
            uint sa2 = (uint)rfl(ca2.x), ea2 = (uint)rfl(ca2.y);
            uint sa3 = (uint)rfl(ca3.x), ea3 = (uint)rfl(ca3.y);
            uint sb0 = (uint)rfl(cb0.x), eb0 = (uint)rfl(cb0.y);
            uint sb1 = (uint)rfl(cb1.x), eb1 = (uint)rfl(cb1.y);
            uint sb2 = (uint)rfl(cb2.x), eb2 = (uint)rfl(cb2.y);
            uint sb3 = (uint)rfl(cb3.x), eb3 = (uint)rfl(cb3.y);
            uint ra0 = ldrow(Ab, t4, sa0), ra1 = ldrow(Ab, t4, sa1);
            uint ra2 = ldrow(Ab, t4, sa2), ra3 = ldrow(Ab, t4, sa3);
            uint rb0 = ldrow(Ab, t4, sb0), rb1 = ldrow(Ab, t4, sb1);
            uint rb2 = ldrow(Ab, t4, sb2), rb3 = ldrow(Ab, t4, sb3);
            accum_edge(ra0, ea0, w0x, w0y, w1x, w1y, ax0, ay0);
            accum_edge(ra1, ea1, w0x, w0y, w1x, w1y, ax0, ay0);
            accum_edge(ra2, ea2, w0x, w0y, w1x, w1y, ax0, ay0);
            accum_edge(ra3, ea3, w0x, w0y, w1x, w1y, ax0, ay0);
            accum_edge(rb0, eb0, w0x, w0y, w1x, w1y, ax1, ay1);
            accum_edge(rb1, eb1, w0x, w0y, w1x, w1y, ax1, ay1);
            accum_edge(rb2, eb2, w0x, w0y, w1x, w1y, ax1, ay1);
            accum_edge(rb3, eb3, w0x, w0y, w1x, w1y, ax1, ay1);
            k0 += 4; k1 += 4;
        }
        drain_node(Ab, t4, csr, k0, e0, w0x, w0y, w1x, w1y, ax0, ay0);
        ts_u[(w * 16 + i) * 68 + t] = (uint)f2bf(ax0) | ((uint)f2bf(ay0) << 16);
        if (h1) {
            drain_node(Ab, t4, csr, k1, e1, w0x, w0y, w1x, w1y, ax1, ay1);
            ts_u[(w * 16 + i + 1) * 68 + t] = (uint)f2bf(ax1) | ((uint)f2bf(ay1) << 16);
        }
    }
}

// ---------------- K3: gather1 + middle GEMMs: A2 = relu(gather(A)@W12+cnt*b12)@W21+b21 ----------------

__global__ __launch_bounds__(256) void gather_mid(
    const uint* __restrict__ Au, const int* __restrict__ ptr,
    const int2* __restrict__ csr, const float* __restrict__ we,
    const ushort* __restrict__ WtA, const float* __restrict__ biasA,
    const ushort* __restrict__ WtB, const float* __restrict__ biasB,
    ushort* __restrict__ Cout, int N) {
    __shared__ uint ts_u[64 * 68];
    ushort* ts = (ushort*)ts_u;
    const int tid = threadIdx.x;
    const int rowBase = blockIdx.x * 64;

    gather_lds(Au, ptr, csr, we, ts_u, N, tid, rowBase);
    __syncthreads();

    const int wave = tid >> 6, lane = tid & 63;
    const int m = lane & 15, quad = lane >> 4;

    bf16x8 bfrag[2][4];
#pragma unroll
    for (int ct = 0; ct < 2; ct++) {
        int col = (wave * 2 + ct) * 16 + m;
#pragma unroll
        for (int ks = 0; ks < 4; ks++)
            bfrag[ct][ks] = *(const bf16x8*)(WtA + (long)col * 128 + ks * 32 + quad * 8);
    }

    f32x4 acc[4][2];
#pragma unroll
    for (int rt = 0; rt < 4; rt++) {
        const ushort* lr = ts + (rt * 16 + m) * 136;
        bf16x8 af[4];
#pragma unroll
        for (int ks = 0; ks < 4; ks++)
            af[ks] = *(const bf16x8*)(lr + ks * 32 + quad * 8);
#pragma unroll
        for (int ct = 0; ct < 2; ct++) {
            f32x4 a = {0.f, 0.f, 0.f, 0.f};
#pragma unroll
            for (int ks = 0; ks < 4; ks++)
                a = __builtin_amdgcn_mfma_f32_16x16x32_bf16(af[ks], bfrag[ct][ks], a, 0, 0, 0);
            acc[rt][ct] = a;
        }
    }
    __syncthreads();   // all ts reads done before overwrite

#pragma unroll
    for (int rt = 0; rt < 4; rt++) {
        float cntf[4];
#pragma unroll
        for (int r = 0; r < 4; r++) {
            long grow = rowBase + rt * 16 + quad * 4 + r;
            cntf[r] = (grow < N) ? (float)(ptr[grow + 1] - ptr[grow] + 1) : 1.f;
        }
#pragma unroll
        for (int ct = 0; ct < 2; ct++) {
            int col = (wave * 2 + ct) * 16 + m;
            float b = biasA[col];
#pragma unroll
            for (int r = 0; r < 4; r++) {
                int row = rt * 16 + quad * 4 + r;
                ts[row * 136 + col] = f2bf(fmaxf(acc[rt][ct][r] + b * cntf[r], 0.f));
            }
        }
    }
    __syncthreads();

#pragma unroll
    for (int ct = 0; ct < 2; ct++) {
        int col = (wave * 2 + ct) * 16 + m;
#pragma unroll
        for (int ks = 0; ks < 4; ks++)
            bfrag[ct][ks] = *(const bf16x8*)(WtB + (long)col * 128 + ks * 32 + quad * 8);
    }
#pragma unroll
    for (int rt = 0; rt < 4; rt++) {
        const ushort* lr = ts + (rt * 16 + m) * 136;
        bf16x8 af[4];
#pragma unroll
        for (int ks = 0; ks < 4; ks++)
            af[ks] = *(const bf16x8*)(lr + ks * 32 + quad * 8);
#pragma unroll
        for (int ct = 0; ct < 2; ct++) {
            f32x4 a = {0.f, 0.f, 0.f, 0.f};
#pragma unroll
            for (int ks = 0; ks < 4; ks++)
                a = __builtin_amdgcn_mfma_f32_16x16x32_bf16(af[ks], bfrag[ct][ks], a, 0, 0, 0);
            int col = (wave * 2 + ct) * 16 + m;
            float b = biasB[col];
#pragma unroll
            for (int r = 0; r < 4; r++) {
                long grow = rowBase + rt * 16 + quad * 4 + r;
                if (grow < N) Cout[grow * 128 + col] = f2bf(a[r] + b);
            }
        }
    }
}

// ---------------- K4: gather2 + last GEMM: out = gather(A2)@W22 + cnt*b22 (f32, nt) ----------------

__global__ __launch_bounds__(256) void gather_out(
    const uint* __restrict__ Au, const int* __restrict__ ptr,
    const int2* __restrict__ csr, const float* __restrict__ we,
    const ushort* __restrict__ Wt, const float* __restrict__ bias,
    float* __restrict__ out, int N) {
    __shared__ uint ts_u[64 * 68];
    ushort* ts = (ushort*)ts_u;
    const int tid = threadIdx.x;
    const int rowBase = blockIdx.x * 64;

    gather_lds(Au, ptr, csr, we, ts_u, N, tid, rowBase);
    __syncthreads();

    const int wave = tid >> 6, lane = tid & 63;
    const int m = lane & 15, quad = lane >> 4;

    bf16x8 bfrag[2][4];
#pragma unroll
    for (int ct = 0; ct < 2; ct++) {
        int col = (wave * 2 + ct) * 16 + m;
#pragma unroll
        for (int ks = 0; ks < 4; ks++)
            bfrag[ct][ks] = *(const bf16x8*)(Wt + (long)col * 128 + ks * 32 + quad * 8);
    }

#pragma unroll
    for (int rt = 0; rt < 4; rt++) {
        const ushort* lr = ts + (rt * 16 + m) * 136;
        bf16x8 af[4];
#pragma unroll
        for (int ks = 0; ks < 4; ks++)
            af[ks] = *(const bf16x8*)(lr + ks * 32 + quad * 8);
        float cntf[4];
#pragma unroll
        for (int r = 0; r < 4; r++) {
            long grow = rowBase + rt * 16 + quad * 4 + r;
            cntf[r] = (grow < N) ? (float)(ptr[grow + 1] - ptr[grow] + 1) : 1.f;
        }
#pragma unroll
        for (int ct = 0; ct < 2; ct++) {
            f32x4 a = {0.f, 0.f, 0.f, 0.f};
#pragma unroll
            for (int ks = 0; ks < 4; ks++)
                a = __builtin_amdgcn_mfma_f32_16x16x32_bf16(af[ks], bfrag[ct][ks], a, 0, 0, 0);
            int col = (wave * 2 + ct) * 16 + m;
            float b = bias[col];
#pragma unroll
            for (int r = 0; r < 4; r++) {
                long grow = rowBase + rt * 16 + quad * 4 + r;
                if (grow < N)
                    __builtin_nontemporal_store(a[r] + b * cntf[r],
                                                &out[grow * 128 + col]);
            }
        }
    }
}

// ---------------- launch ----------------

extern "C" void kernel_launch(void* const* d_in, const int* in_sizes, int n_in,
                              void* d_out, int out_size, void* d_ws, size_t ws_size,
                              hipStream_t stream) {
    const float* x   = (const float*)d_in[0];
    const int*   ei  = (const int*)d_in[1];
    const float* ea  = (const float*)d_in[2];
    const float* W11 = (const float*)d_in[3];
    const float* b11 = (const float*)d_in[4];
    const float* W12 = (const float*)d_in[5];
    const float* b12 = (const float*)d_in[6];
    const float* W21 = (const float*)d_in[7];
    const float* b21 = (const float*)d_in[8];
    const float* W22 = (const float*)d_in[9];
    const float* b22 = (const float*)d_in[10];
    float* out = (float*)d_out;

    const int N = in_sizes[0] / 64;
    const int E = in_sizes[1] / 2;
    const int* src = ei;
    const int* dst = ei + E;

    const int B = (N + BNODES - 1) >> BSHIFT;     // 196 buckets
    const int CAP = E / B + 4096;                 // per-bucket capacity

    char* p = (char*)d_ws;
    ushort* A_bf = (ushort*)p;        p += (size_t)N * 128 * 2;   // 25.6 MB
    ushort* A2_bf = (ushort*)p;
    int2* barr = (int2*)A2_bf;        p += (size_t)N * 128 * 2;   // 25.6 MB (alias: barr consumed in K2 before A2 written in K3)
    int2* csr  = (int2*)p;            p += (size_t)E * 8;         // 12.8 MB
    int* ptr   = (int*)p;             p += (size_t)(N + 1) * 4;
    int* bcnt  = (int*)p;             p += 256 * 4;
    ushort* Wt11 = (ushort*)p;        p += (size_t)64 * 128 * 2;
    ushort* Wt12 = (ushort*)p;        p += (size_t)128 * 128 * 2;
    ushort* Wt21 = (ushort*)p;        p += (size_t)128 * 128 * 2;
    ushort* Wt22 = (ushort*)p;

    const int WB = (448 * 128 + 511) / 512;       // 112 wprep blocks
    const int binBlocks = (E + 4095) / 4096;      // 391
    const int tileBlocks = (N + 63) / 64;         // 1563
    const int g1Tiles = (N + 127) / 128;          // 782 (128-row tiles, 512 thr)

    hipMemsetAsync(bcnt, 0, 256 * sizeof(int), stream);
    // K1: weight transpose || edge binning (independent)
    wprep_bin<<<WB + binBlocks, 512, 0, stream>>>(
        W11, W12, W21, W22, Wt11, Wt12, Wt21, Wt22,
        src, dst, ea, bcnt, barr, CAP, N, E, B, WB, ptr);
    // K2: csr build || layer-1 gemm (independent)
    csr_gemm1<<<B + g1Tiles, 512, 0, stream>>>(barr, bcnt, CAP, N, csr, ptr, B,
                                               x, Wt11, b11, A_bf);
    // K3: gather(A) + relu-GEMM + GEMM -> A2  (B never hits HBM)
    gather_mid<<<tileBlocks, 256, 0, stream>>>((const uint*)A_bf, ptr, csr,
                                               W11 + 64 * 128, Wt12, b12, Wt21, b21,
                                               A2_bf, N);
    // K4: gather(A2) + GEMM -> out  (B2 never hits HBM)
    gather_out<<<tileBlocks, 256, 0, stream>>>((const uint*)A2_bf, ptr, csr,
                                               W21 + 128 * 128, Wt22, b22, out, N);
}

// Round 8
// 370.481 us; speedup vs baseline: 2.5580x; 1.2541x over previous
//
#include <hip/hip_runtime.h>

// GIN (2x GINE conv): bucketed CSR build + standalone scalarized CSR gathers
// + bf16 MFMA GEMMs. 6 launches + 1 memset:
//   M0 memset bcnt=0
//   K1 wprep||bin  (blocks<WB transpose weights; rest: 4096-edge LDS sort)
//   K2 csr||gemm1  (196 csr blocks + 782 gemm tiles; independent work)
//   K3 gather1: A -> B          (1 node/wave, 8-deep batches, nt store)
//   K4 fused_mid: relu(B@W12+cnt*b12)@W21+b21 -> A2   (through LDS)
//   K5 gather2: A2 -> B2
//   K6 B2 @ W22 + cnt*b22 -> out (f32, nt)
// R2/R3/R7 verdict: fusing gather with MFMA in one block runs the gather at
// ~2x its standalone time at ANY tile size / occupancy / interleave (three
// falsified mechanisms) -> standalone gathers only. Gather floor is
// structural: FETCH ~198MB = 8 XCDs x 25.6MB A (random src >> 4MB L2/XCD),
// ~59.4us each at the observed L3->L2 serve rate; VALU ~10 ops/edge ~ 33us.

typedef unsigned int uint;
typedef unsigned short ushort;
typedef __attribute__((ext_vector_type(8))) short bf16x8;
typedef __attribute__((ext_vector_type(4))) float f32x4;

#define BSHIFT 9             // 512 nodes per bucket -> 196 buckets
#define BNODES (1 << BSHIFT)

static __device__ __forceinline__ ushort f2bf(float f) {
    uint u = __float_as_uint(f);
    uint r = (u + 0x7fffu + ((u >> 16) & 1u)) >> 16;
    return (ushort)r;
}
static __device__ __forceinline__ int rfl(int v) { return __builtin_amdgcn_readfirstlane(v); }

// ---------------- K1: weight prep (blocks < WB) || edge binning (rest) ----------------
// bin: entry.x = src | (dloc<<17) (src<2^17, dloc<2^9), entry.y = ea bf16x2

__global__ __launch_bounds__(512) void wprep_bin(
    const float* __restrict__ W11, const float* __restrict__ W12,
    const float* __restrict__ W21, const float* __restrict__ W22,
    ushort* Wt11, ushort* Wt12, ushort* Wt21, ushort* Wt22,
    const int* __restrict__ src, const int* __restrict__ dst,
    const float* __restrict__ ea, int* __restrict__ bcnt,
    int2* __restrict__ barr, int CAP, int N, int E, int B, int WB,
    int* __restrict__ ptr) {
    __shared__ int hist[256];
    __shared__ int bbase[256];
    __shared__ int gbase[256];
    __shared__ int wtot[4];
    __shared__ int2 sorted[4096];
    __shared__ unsigned char bof[4096];
    const int tid = threadIdx.x;
    const int lane = tid & 63;

    if ((int)blockIdx.x < WB) {
        // ---- weight transpose: W[K][128] f32 -> Wt[128][K] bf16 ----
        int idx = blockIdx.x * 512 + tid;
        if (idx == 0) ptr[N] = E;
        if (idx < 448 * 128) {
            const float* W; ushort* Wt; int K; int off;
            if (idx < 64 * 128)        { W = W11; Wt = Wt11; K = 64;  off = idx; }
            else if (idx < 192 * 128)  { W = W12; Wt = Wt12; K = 128; off = idx - 64 * 128; }
            else if (idx < 320 * 128)  { W = W21; Wt = Wt21; K = 128; off = idx - 192 * 128; }
            else                       { W = W22; Wt = Wt22; K = 128; off = idx - 320 * 128; }
            int k = off >> 7, n = off & 127;
            Wt[n * K + k] = f2bf(W[k * 128 + n]);
        }
        return;
    }

    // ---- binning: 4096-edge tile sort in LDS, coalesced chunk appends ----
    const int tileBase = ((int)blockIdx.x - WB) * 4096;
    int n = E - tileBase; if (n > 4096) n = 4096; if (n <= 0) return;
    if (tid < 256) hist[tid] = 0;
    __syncthreads();

    int2 ent[8]; int bk[8]; int rk[8];
#pragma unroll
    for (int kk = 0; kk < 8; kk++) {
        int i = kk * 512 + tid;
        bk[kk] = -1;
        if (i < n) {
            int e = tileBase + i;
            int s = src[e], d = dst[e];
            float2 a = reinterpret_cast<const float2*>(ea)[e];
            int b = d >> BSHIFT;
            int dloc = d & (BNODES - 1);
            ent[kk].x = s | (dloc << 17);
            ent[kk].y = (int)((uint)f2bf(a.x) | ((uint)f2bf(a.y) << 16));
            bk[kk] = b;
            rk[kk] = atomicAdd(&hist[b], 1);
        }
    }
    __syncthreads();
    int hv = (tid < 256) ? hist[tid] : 0;
    int inc = hv;
#pragma unroll
    for (int off = 1; off < 64; off <<= 1) {
        int tt = __shfl_up(inc, off, 64);
        if (lane >= off) inc += tt;
    }
    if ((tid >> 6) < 4 && lane == 63) wtot[tid >> 6] = inc;
    __syncthreads();
    if (tid == 0) { int run = 0; for (int i = 0; i < 4; i++) { int tt = wtot[i]; wtot[i] = run; run += tt; } }
    __syncthreads();
    if (tid < 256) bbase[tid] = inc - hv + wtot[tid >> 6];
    if (tid < B && hv > 0) gbase[tid] = atomicAdd(&bcnt[tid], hv);
    __syncthreads();
#pragma unroll
    for (int kk = 0; kk < 8; kk++) {
        if (bk[kk] >= 0) {
            int p = bbase[bk[kk]] + rk[kk];
            sorted[p] = ent[kk];
            bof[p] = (unsigned char)bk[kk];
        }
    }
    __syncthreads();
    for (int i = tid; i < n; i += 512) {
        int b = bof[i];
        barr[(long)b * CAP + gbase[b] + (i - bbase[b])] = sorted[i];
    }
}

// ---------------- per-bucket exact CSR (512-node bucket, 512 threads) ----------------

static __device__ void csr_body(const int2* __restrict__ barr, const int* __restrict__ bcnt,
                                int CAP, int N, int2* __restrict__ csr, int* __restrict__ ptr) {
    __shared__ int hist[BNODES];
    __shared__ int lptr[BNODES];
    __shared__ int wtot[8];
    __shared__ int sbase;
    const int g = blockIdx.x;
    const int tid = threadIdx.x;
    const int lane = tid & 63;
    const int cnt = bcnt[g];
    if (tid == 0) sbase = 0;
    hist[tid] = 0;
    __syncthreads();
    if (tid < g) atomicAdd(&sbase, bcnt[tid]);   // bucket base (parallel)
    const int2* my = barr + (long)g * CAP;
    for (int i = tid; i < cnt; i += 512)
        atomicAdd(&hist[((uint)my[i].x) >> 17], 1);
    __syncthreads();
    int v = hist[tid];
    int inc = v;
#pragma unroll
    for (int off = 1; off < 64; off <<= 1) {
        int tt = __shfl_up(inc, off, 64);
        if (lane >= off) inc += tt;
    }
    if (lane == 63) wtot[tid >> 6] = inc;
    __syncthreads();
    if (tid == 0) { int run = 0; for (int i = 0; i < 8; i++) { int tt = wtot[i]; wtot[i] = run; run += tt; } }
    __syncthreads();
    const int base = sbase;
    int excl = inc - v + wtot[tid >> 6];
    lptr[tid] = excl;
    int gnode = g * BNODES + tid;
    if (gnode < N) ptr[gnode] = base + excl;
    __syncthreads();
    for (int i = tid; i < cnt; i += 512) {
        int2 e = my[i];
        int pos = base + atomicAdd(&lptr[((uint)e.x) >> 17], 1);
        int2 o; o.x = e.x & 0x1FFFF; o.y = e.y;
        csr[pos] = o;
    }
}

// ---------------- MFMA GEMM body: C[rowBase..+64][128] = A @ W[K][128] + bias ----------------
// f32 output path uses nt stores (out is never re-read on device).

template <int K, bool IN_F32, bool OUT_BF16, bool USE_CNT>
static __device__ __forceinline__ void gemm_body(
    const void* __restrict__ Ain, const ushort* __restrict__ Wt,
    const float* __restrict__ bias, const int* __restrict__ ptr,
    void* __restrict__ Cout, int N, int tid, long rowBase) {
    constexpr int KS = K / 32;
    const int wave = tid >> 6;
    const int lane = tid & 63;
    const int m = lane & 15, quad = lane >> 4;

    bf16x8 bfrag[2][KS];
#pragma unroll
    for (int ct = 0; ct < 2; ct++) {
        int col = (wave * 2 + ct) * 16 + m;
#pragma unroll
        for (int ks = 0; ks < KS; ks++)
            bfrag[ct][ks] = *(const bf16x8*)(Wt + (long)col * K + ks * 32 + quad * 8);
    }

#pragma unroll
    for (int rt = 0; rt < 4; rt++) {
        long row = rowBase + rt * 16 + m;
        long rc = row < N ? row : (long)N - 1;
        bf16x8 afrag[KS];
        if (IN_F32) {
            const float* arow = (const float*)Ain + rc * K;
#pragma unroll
            for (int ks = 0; ks < KS; ks++) {
                float4 lo = *(const float4*)(arow + ks * 32 + quad * 8);
                float4 hi = *(const float4*)(arow + ks * 32 + quad * 8 + 4);
                bf16x8 f;
                f[0] = (short)f2bf(lo.x); f[1] = (short)f2bf(lo.y);
                f[2] = (short)f2bf(lo.z); f[3] = (short)f2bf(lo.w);
                f[4] = (short)f2bf(hi.x); f[5] = (short)f2bf(hi.y);
                f[6] = (short)f2bf(hi.z); f[7] = (short)f2bf(hi.w);
                afrag[ks] = f;
            }
        } else {
            const ushort* arow = (const ushort*)Ain + rc * K;
#pragma unroll
            for (int ks = 0; ks < KS; ks++)
                afrag[ks] = *(const bf16x8*)(arow + ks * 32 + quad * 8);
        }

#pragma unroll
        for (int ct = 0; ct < 2; ct++) {
            f32x4 acc = {0.f, 0.f, 0.f, 0.f};
#pragma unroll
            for (int ks = 0; ks < KS; ks++)
                acc = __builtin_amdgcn_mfma_f32_16x16x32_bf16(afrag[ks], bfrag[ct][ks], acc, 0, 0, 0);

            int col = (wave * 2 + ct) * 16 + m;
            float b = bias[col];
#pragma unroll
            for (int r = 0; r < 4; r++) {
                long orow = rowBase + rt * 16 + quad * 4 + r;
                if (orow < N) {
                    float v = acc[r];
                    if (USE_CNT) v += b * (float)(ptr[orow + 1] - ptr[orow] + 1);
                    else v += b;
                    if (OUT_BF16) ((ushort*)Cout)[orow * 128 + col] = f2bf(v);
                    else __builtin_nontemporal_store(v, (float*)Cout + orow * 128 + col);
                }
            }
        }
    }
}

// ---------------- K2: bucket CSR (blocks < B) || layer-1 GEMM ----------------

__global__ __launch_bounds__(512) void csr_gemm1(
    const int2* __restrict__ barr, const int* __restrict__ bcnt, int CAP, int N,
    int2* __restrict__ csr, int* __restrict__ ptr, int CSRB,
    const float* __restrict__ x, const ushort* __restrict__ Wt11,
    const float* __restrict__ b11, ushort* __restrict__ A_bf) {
    if ((int)blockIdx.x < CSRB) {
        csr_body(barr, bcnt, CAP, N, csr, ptr);
    } else {
        int bid = blockIdx.x - CSRB;
        int sub = threadIdx.x >> 8;  // two 64-row tiles per 512-thread block
        gemm_body<64, true, true, false>(x, Wt11, b11, nullptr, A_bf, N,
                                         threadIdx.x & 255,
                                         (long)bid * 128 + sub * 64);
    }
}

// ---------------- K3/K5: CSR gather, wave/node, scalarized edge stream (R1-proven 59.4us) ----------------

__global__ __launch_bounds__(256) void gather_kernel(
    const uint* __restrict__ Au, const int* __restrict__ ptr,
    const int2* __restrict__ csr, const float* __restrict__ we,
    uint* __restrict__ Bout, int N) {
    int node = blockIdx.x * 4 + (threadIdx.x >> 6);
    if (node >= N) return;
    node = rfl(node);
    const int t = threadIdx.x & 63;
    const int c = 2 * t;
    const float w0x = we[c], w0y = we[c + 1];
    const float w1x = we[128 + c], w1y = we[128 + c + 1];

    const char* Ab = (const char*)Au;
    const uint t4 = (uint)t * 4u;
#define LD(sidx) (*(const uint*)(Ab + ((((uint)(sidx)) << 8) + t4)))
#define ACC(rv, ev)                                                      \
    {                                                                    \
        float a0 = __uint_as_float(((uint)(ev)) << 16);                  \
        float a1 = __uint_as_float(((uint)(ev)) & 0xffff0000u);          \
        float vx = __uint_as_float((rv) << 16);                          \
        float vy = __uint_as_float((rv) & 0xffff0000u);                  \
        vx = fmaf(a0, w0x, fmaf(a1, w1x, vx));                           \
        vy = fmaf(a0, w0y, fmaf(a1, w1y, vy));                           \
        ax += fmaxf(vx, 0.f);                                            \
        ay += fmaxf(vy, 0.f);                                            \
    }
#define EDGE(i, off)                                                     \
    int2 c##i = csr[k + (off)];                                          \
    uint s##i = (uint)rfl(c##i.x);                                       \
    uint e##i = (uint)rfl(c##i.y);

    uint selfv = LD((uint)node);
    float ax = fmaxf(__uint_as_float(selfv << 16) + w0x + w1x, 0.f);
    float ay = fmaxf(__uint_as_float(selfv & 0xffff0000u) + w0y + w1y, 0.f);

    // wave-uniform edge range -> scalar loop control + scalar csr loads
    int k   = rfl(ptr[node]);
    int end = rfl(ptr[node + 1]);

    for (; k + 8 <= end; k += 8) {
        EDGE(0, 0) EDGE(1, 1) EDGE(2, 2) EDGE(3, 3)
        EDGE(4, 4) EDGE(5, 5) EDGE(6, 6) EDGE(7, 7)
        uint r0 = LD(s0); uint r1 = LD(s1); uint r2 = LD(s2); uint r3 = LD(s3);
        uint r4 = LD(s4); uint r5 = LD(s5); uint r6 = LD(s6); uint r7 = LD(s7);
        ACC(r0, e0) ACC(r1, e1) ACC(r2, e2) ACC(r3, e3)
        ACC(r4, e4) ACC(r5, e5) ACC(r6, e6) ACC(r7, e7)
    }
    for (; k + 2 <= end; k += 2) {
        EDGE(0, 0) EDGE(1, 1)
        uint r0 = LD(s0); uint r1 = LD(s1);
        ACC(r0, e0) ACC(r1, e1)
    }
    if (k < end) {
        EDGE(0, 0)
        uint r0 = LD(s0);
        ACC(r0, e0)
    }
#undef EDGE
#undef ACC
#undef LD
    uint outv = (uint)f2bf(ax) | ((uint)f2bf(ay) << 16);
    // nt store: B is streamed; don't evict A's L2 lines
    __builtin_nontemporal_store(outv, Bout + (long)node * 64 + t);
}

// ---------------- K4: fused middle GEMMs: A2 = (relu(B@W12 + cnt*b12)) @ W21 + b21 ----------------

__global__ __launch_bounds__(256) void fused_mid_gemm(
    const ushort* __restrict__ Bin, const int* __restrict__ ptr,
    const ushort* __restrict__ WtA, const float* __restrict__ biasA,
    const ushort* __restrict__ WtB, const float* __restrict__ biasB,
    ushort* __restrict__ Cout, int N) {
    __shared__ ushort ts[64 * 136];
    const int wave = threadIdx.x >> 6;
    const int lane = threadIdx.x & 63;
    const int m = lane & 15, quad = lane >> 4;
    const long rowBase = (long)blockIdx.x * 64;

    bf16x8 bfrag[2][4];
#pragma unroll
    for (int ct = 0; ct < 2; ct++) {
        int col = (wave * 2 + ct) * 16 + m;
#pragma unroll
        for (int ks = 0; ks < 4; ks++)
            bfrag[ct][ks] = *(const bf16x8*)(WtA + (long)col * 128 + ks * 32 + quad * 8);
    }

    f32x4 acc[4][2];
#pragma unroll
    for (int rt = 0; rt < 4; rt++) {
        long row = rowBase + rt * 16 + m;
        long rc = row < N ? row : (long)N - 1;
        const ushort* arow = Bin + rc * 128;
        bf16x8 af[4];
#pragma unroll
        for (int ks = 0; ks < 4; ks++)
            af[ks] = *(const bf16x8*)(arow + ks * 32 + quad * 8);
#pragma unroll
        for (int ct = 0; ct < 2; ct++) {
            f32x4 a = {0.f, 0.f, 0.f, 0.f};
#pragma unroll
            for (int ks = 0; ks < 4; ks++)
                a = __builtin_amdgcn_mfma_f32_16x16x32_bf16(af[ks], bfrag[ct][ks], a, 0, 0, 0);
            acc[rt][ct] = a;
        }
    }

#pragma unroll
    for (int rt = 0; rt < 4; rt++) {
        float cntf[4];
#pragma unroll
        for (int r = 0; r < 4; r++) {
            long grow = rowBase + rt * 16 + quad * 4 + r;
            cntf[r] = (grow < N) ? (float)(ptr[grow + 1] - ptr[grow] + 1) : 1.f;
        }
#pragma unroll
        for (int ct = 0; ct < 2; ct++) {
            int col = (wave * 2 + ct) * 16 + m;
            float b = biasA[col];
#pragma unroll
            for (int r = 0; r < 4; r++) {
                int row = rt * 16 + quad * 4 + r;
                ts[row * 136 + col] = f2bf(fmaxf(acc[rt][ct][r] + b * cntf[r], 0.f));
            }
        }
    }
    __syncthreads();

#pragma unroll
    for (int ct = 0; ct < 2; ct++) {
        int col = (wave * 2 + ct) * 16 + m;
#pragma unroll
        for (int ks = 0; ks < 4; ks++)
            bfrag[ct][ks] = *(const bf16x8*)(WtB + (long)col * 128 + ks * 32 + quad * 8);
    }
#pragma unroll
    for (int rt = 0; rt < 4; rt++) {
        const ushort* lr = ts + (rt * 16 + m) * 136;
        bf16x8 af[4];
#pragma unroll
        for (int ks = 0; ks < 4; ks++)
            af[ks] = *(const bf16x8*)(lr + ks * 32 + quad * 8);
#pragma unroll
        for (int ct = 0; ct < 2; ct++) {
            f32x4 a = {0.f, 0.f, 0.f, 0.f};
#pragma unroll
            for (int ks = 0; ks < 4; ks++)
                a = __builtin_amdgcn_mfma_f32_16x16x32_bf16(af[ks], bfrag[ct][ks], a, 0, 0, 0);
            int col = (wave * 2 + ct) * 16 + m;
            float b = biasB[col];
#pragma unroll
            for (int r = 0; r < 4; r++) {
                long grow = rowBase + rt * 16 + quad * 4 + r;
                if (grow < N) Cout[grow * 128 + col] = f2bf(a[r] + b);
            }
        }
    }
}

// ---------------- K6: last GEMM wrapper ----------------

template <int K, bool IN_F32, bool OUT_BF16, bool USE_CNT>
__global__ __launch_bounds__(256) void gemm_mfma(
    const void* __restrict__ Ain, const ushort* __restrict__ Wt,
    const float* __restrict__ bias, const int* __restrict__ ptr,
    void* __restrict__ Cout, int N) {
    gemm_body<K, IN_F32, OUT_BF16, USE_CNT>(Ain, Wt, bias, ptr, Cout, N,
                                            threadIdx.x, (long)blockIdx.x * 64);
}

// ---------------- launch ----------------

extern "C" void kernel_launch(void* const* d_in, const int* in_sizes, int n_in,
                              void* d_out, int out_size, void* d_ws, size_t ws_size,
                              hipStream_t stream) {
    const float* x   = (const float*)d_in[0];
    const int*   ei  = (const int*)d_in[1];
    const float* ea  = (const float*)d_in[2];
    const float* W11 = (const float*)d_in[3];
    const float* b11 = (const float*)d_in[4];
    const float* W12 = (const float*)d_in[5];
    const float* b12 = (const float*)d_in[6];
    const float* W21 = (const float*)d_in[7];
    const float* b21 = (const float*)d_in[8];
    const float* W22 = (const float*)d_in[9];
    const float* b22 = (const float*)d_in[10];
    float* out = (float*)d_out;

    const int N = in_sizes[0] / 64;
    const int E = in_sizes[1] / 2;
    const int* src = ei;
    const int* dst = ei + E;

    const int B = (N + BNODES - 1) >> BSHIFT;     // 196 buckets
    const int CAP = E / B + 4096;                 // per-bucket capacity

    char* p = (char*)d_ws;
    ushort* A_bf = (ushort*)p;        p += (size_t)N * 128 * 2;   // 25.6 MB
    ushort* B_bf = (ushort*)p;
    int2* barr = (int2*)B_bf;         p += (size_t)N * 128 * 2;   // 25.6 MB (alias: barr consumed in K2 before B written in K3)
    int2* csr  = (int2*)p;            p += (size_t)E * 8;         // 12.8 MB
    int* ptr   = (int*)p;             p += (size_t)(N + 1) * 4;
    int* bcnt  = (int*)p;             p += 256 * 4;
    ushort* Wt11 = (ushort*)p;        p += (size_t)64 * 128 * 2;
    ushort* Wt12 = (ushort*)p;        p += (size_t)128 * 128 * 2;
    ushort* Wt21 = (ushort*)p;        p += (size_t)128 * 128 * 2;
    ushort* Wt22 = (ushort*)p;

    const int WB = (448 * 128 + 511) / 512;       // 112 wprep blocks
    const int binBlocks = (E + 4095) / 4096;      // 391
    const int gatherBlocks = (N + 3) / 4;         // 25000
    const int tileBlocks = (N + 63) / 64;         // 1563
    const int g1Tiles = (N + 127) / 128;          // 782 (128-row tiles, 512 thr)

    hipMemsetAsync(bcnt, 0, 256 * sizeof(int), stream);
    // K1: weight transpose || edge binning (independent)
    wprep_bin<<<WB + binBlocks, 512, 0, stream>>>(
        W11, W12, W21, W22, Wt11, Wt12, Wt21, Wt22,
        src, dst, ea, bcnt, barr, CAP, N, E, B, WB, ptr);
    // K2: csr build || layer-1 gemm (independent)
    csr_gemm1<<<B + g1Tiles, 512, 0, stream>>>(barr, bcnt, CAP, N, csr, ptr, B,
                                               x, Wt11, b11, A_bf);
    // K3: gather1  A -> B
    gather_kernel<<<gatherBlocks, 256, 0, stream>>>((const uint*)A_bf, ptr, csr,
                                                    W11 + 64 * 128, (uint*)B_bf, N);
    // K4: fused middle GEMMs  B -> A2 (reuses A_bf)
    fused_mid_gemm<<<tileBlocks, 256, 0, stream>>>(B_bf, ptr, Wt12, b12, Wt21, b21, A_bf, N);
    // K5: gather2  A2 -> B2 (reuses B_bf)
    gather_kernel<<<gatherBlocks, 256, 0, stream>>>((const uint*)A_bf, ptr, csr,
                                                    W21 + 128 * 128, (uint*)B_bf, N);
    // K6: final GEMM -> out (f32, nt)
    gemm_mfma<128, false, false, true><<<tileBlocks, 256, 0, stream>>>(
        B_bf, Wt22, b22, ptr, out, N);
}